// Round 7
// baseline (278.303 us; speedup 1.0000x reference)
//
#include <hip/hip_runtime.h>
#include <math.h>

#define WAVE 64
#define BINSHIFT 9                  // 512 nodes per bin
#define NPB 512                     // nodes per bin
#define NBLK 512                    // edge-tile blocks for hist/place (also scan block size)
#define MAXBINS 256                 // LDS histogram capacity (actual nbins = 196)
#define BINCAP 17408                // per-bin capacity; mean 16384, sd ~128 -> +8 sigma
// record packing: src < 2^17, dstLow < 512 -> rec = (dstLow<<17)|src fits 26 bits
//
// Round 5/7: per-edge global atomicAdd ~100+ MB fabric RMW -> build is atomic-free.
// Round 8: layer-2 agg L2-miss BW-bound -> gathered feature buffers bf16.
// Round 9/10: device atomicMax on sorted batch serializes -> atomic-free epilogue.
// Round 11/12/13: place_k scatter amp fixed via coarse bins (128 B segments).
// Round 14/15/16: fp8-e4m3 staging for layer-2/3 gathers.
// Round 17/18: MFMA gemm23 (16x16x32 bf16) replaced LDS-issue-bound scalar gemm.
// Round 19: bin_sort 1024 thr. Round 20: fuse agg1+gemm1.
// Round 21 FAILED: agg2+gemm23 fusion coupled gather behind barriers (67us).
// Round 22/23 FAILED (315.9): channel-split kept req/edge high, doubled csr.
// Round 24/25 FAILED (286.5/283.6): row & pair-row gathers. Sliver gathers win:
//   high occupancy + decoupled loads; row forms lose to VGPR pressure.
// Round 26 NEUTRAL (271.0): R0 restored + fp8 Bf8 staging (passes, halves
//   agg2<->gemm23 round trip). All kernels < 43us fill floor.
// Round 27: widened slivers within the proven structure. agg2: G=16x4B ->
//   G=8x8B (16->8 req/edge, acc 8 f32). agg34: G=8x4B -> G=4x8B (8->4
//   req/edge, acc 8 f32, epilogue 8ch/lane, reduce masks {2,1}). Only these
//   two kernels + grids changed vs R26.

typedef int vint4 __attribute__((ext_vector_type(4)));
typedef unsigned int uint;
typedef unsigned char uchar;
typedef __attribute__((ext_vector_type(8))) short bf16x8;
typedef __attribute__((ext_vector_type(4))) float f32x4;

__device__ inline float bflo(uint u) { return __uint_as_float(u << 16); }
__device__ inline float bfhi(uint u) { return __uint_as_float(u & 0xffff0000u); }
__device__ inline uint pack_bf2(float a, float b) {   // a->low16, b->high16, RNE
    uint ua = __float_as_uint(a), ub = __float_as_uint(b);
    uint ra = (ua + 0x7fffu + ((ua >> 16) & 1u)) >> 16;
    uint rb = (ub + 0x7fffu + ((ub >> 16) & 1u)) & 0xffff0000u;
    return ra | rb;
}
__device__ inline ushort bf16r(float f) {             // RNE to bf16
    uint u = __float_as_uint(f);
    u += 0x7fffu + ((u >> 16) & 1u);
    return (ushort)(u >> 16);
}

// ---- fp8 e4m3fn (OCP) pack/unpack: HW cvt on gfx950, manual fallback ----

#if defined(__HIP_DEVICE_COMPILE__) && __has_builtin(__builtin_amdgcn_cvt_pk_f32_fp8) && __has_builtin(__builtin_amdgcn_cvt_pk_fp8_f32)
#define FP8_HW 1
#else
#define FP8_HW 0
#endif

__device__ inline uint fp8_enc1(float x) {            // manual e4m3fn encode, RNE
    float cx = fminf(fmaxf(x, -448.f), 448.f);
    uint s = (__float_as_uint(cx) >> 24) & 0x80u;
    float ax = fabsf(cx);
    uint r = __float_as_uint(ax);
    uint keep = r >> 20;
    uint rem = r & 0xFFFFFu;
    keep += (rem > 0x80000u || (rem == 0x80000u && (keep & 1u))) ? 1u : 0u;
    int em = (int)keep - (120 << 3);
    uint sub = (uint)__float2int_rn(ax * 512.f);      // subnormal grid 2^-9
    uint v = (ax >= 0.015625f) ? (uint)(em > 0x7E ? 0x7E : em) : sub;
    return s | v;
}
__device__ inline float fp8_dec1(uint b) {            // manual e4m3fn decode
    uint s = (b & 0x80u) << 24;
    uint em = b & 0x7Fu;
    float mag = (em >= 8u)
        ? __uint_as_float((((em >> 3) + 120u) << 23) | ((em & 7u) << 20))
        : (float)em * 0.001953125f;
    return __uint_as_float(s | __float_as_uint(mag));
}

__device__ inline uint fp8x4_enc(float a0, float a1, float a2, float a3) {
#if FP8_HW
    int v = __builtin_amdgcn_cvt_pk_fp8_f32(a0, a1, 0, 0);
    v     = __builtin_amdgcn_cvt_pk_fp8_f32(a2, a3, v, 1);
    return (uint)v;
#else
    return fp8_enc1(a0) | (fp8_enc1(a1) << 8) | (fp8_enc1(a2) << 16) | (fp8_enc1(a3) << 24);
#endif
}
__device__ inline void fp8x4_dec(uint u, float& a0, float& a1, float& a2, float& a3) {
#if FP8_HW
    auto lo = __builtin_amdgcn_cvt_pk_f32_fp8((int)u, 0);
    auto hi = __builtin_amdgcn_cvt_pk_f32_fp8((int)u, 1);
    a0 = lo[0]; a1 = lo[1]; a2 = hi[0]; a3 = hi[1];
#else
    a0 = fp8_dec1(u & 0xffu); a1 = fp8_dec1((u >> 8) & 0xffu);
    a2 = fp8_dec1((u >> 16) & 0xffu); a3 = fp8_dec1(u >> 24);
#endif
}

__device__ inline bf16x8 fp8x8_bf16(uint lo, uint hi) {   // exact fp8->bf16
    float f0, f1, f2, f3, f4, f5, f6, f7;
    fp8x4_dec(lo, f0, f1, f2, f3);
    fp8x4_dec(hi, f4, f5, f6, f7);
    union { uint u[4]; bf16x8 v; } c;
    c.u[0] = pack_bf2(f0, f1);
    c.u[1] = pack_bf2(f2, f3);
    c.u[2] = pack_bf2(f4, f5);
    c.u[3] = pack_bf2(f6, f7);
    return c.v;
}

// ---------------- pass 1: per-block LDS histogram by bin (1024 thr) ----------------

__global__ __launch_bounds__(1024) void hist_k(const int* __restrict__ ei, int* __restrict__ counts,
                                               int E, int nbins) {
    __shared__ int scnt[MAXBINS];
    int t = threadIdx.x, b = blockIdx.x;
    if (t < nbins) scnt[t] = 0;
    __syncthreads();
    int nq  = E >> 2;
    int qpb = (nq + NBLK - 1) / NBLK;
    int q0 = b * qpb, q1 = min(q0 + qpb, nq);
    for (int q = q0 + t; q < q1; q += 1024) {
        vint4 d4 = __builtin_nontemporal_load(reinterpret_cast<const vint4*>(ei + E + q * 4));
        atomicAdd(&scnt[d4.x >> BINSHIFT], 1);
        atomicAdd(&scnt[d4.y >> BINSHIFT], 1);
        atomicAdd(&scnt[d4.z >> BINSHIFT], 1);
        atomicAdd(&scnt[d4.w >> BINSHIFT], 1);
    }
    if (b == NBLK - 1 && t == 0)
        for (int e = (E & ~3); e < E; ++e) atomicAdd(&scnt[ei[E + e] >> BINSHIFT], 1);
    __syncthreads();
    if (t < nbins) counts[b * nbins + t] = scnt[t];
}

// ---------------- scan (+ graph starts + sentinel pads) ----------------

__global__ __launch_bounds__(NBLK) void scan_k(const int* __restrict__ counts, int* __restrict__ prefix,
                                               int* __restrict__ totals, const int* __restrict__ batch,
                                               int* __restrict__ gstart, ushort* __restrict__ padX,
                                               uint* __restrict__ pad8, int nbins, int N, int Gn) {
    __shared__ int sm[NBLK];
    int bin = blockIdx.x, t = threadIdx.x;
    int v = counts[t * nbins + bin];
    sm[t] = v;
    __syncthreads();
    for (int off = 1; off < NBLK; off <<= 1) {
        int x = (t >= off) ? sm[t - off] : 0;
        __syncthreads();
        sm[t] += x;
        __syncthreads();
    }
    prefix[t * nbins + bin] = sm[t] - v;
    if (t == NBLK - 1) totals[bin] = sm[t];
    int gtid = bin * NBLK + t;
    if (gtid < N) {
        int bi = batch[gtid];
        int bp = (gtid == 0) ? -1 : batch[gtid - 1];
        for (int g = bp + 1; g <= bi; ++g) gstart[g] = gtid;
        if (gtid == N - 1)
            for (int g = bi + 1; g <= Gn; ++g) gstart[g] = N;
    }
    if (gtid < 128) padX[gtid] = 0;
    if (gtid < 64)  pad8[gtid] = 0;
}

// ---------------- pass 2: deterministic placement (1024 thr) ----------------

__global__ __launch_bounds__(1024) void place_k(const int* __restrict__ ei, const int* __restrict__ prefix,
                                                int* __restrict__ binned, int E, int nbins) {
    __shared__ int soff[MAXBINS];
    int t = threadIdx.x, b = blockIdx.x;
    if (t < nbins) soff[t] = prefix[b * nbins + t];
    __syncthreads();
    int nq  = E >> 2;
    int qpb = (nq + NBLK - 1) / NBLK;
    int q0 = b * qpb, q1 = min(q0 + qpb, nq);
    for (int q = q0 + t; q < q1; q += 1024) {
        vint4 s4 = __builtin_nontemporal_load(reinterpret_cast<const vint4*>(ei + q * 4));
        vint4 d4 = __builtin_nontemporal_load(reinterpret_cast<const vint4*>(ei + E + q * 4));
        int bb, p;
        bb = d4.x >> BINSHIFT; p = atomicAdd(&soff[bb], 1);
        if (p < BINCAP) binned[bb * BINCAP + p] = ((d4.x & (NPB - 1)) << 17) | s4.x;
        bb = d4.y >> BINSHIFT; p = atomicAdd(&soff[bb], 1);
        if (p < BINCAP) binned[bb * BINCAP + p] = ((d4.y & (NPB - 1)) << 17) | s4.y;
        bb = d4.z >> BINSHIFT; p = atomicAdd(&soff[bb], 1);
        if (p < BINCAP) binned[bb * BINCAP + p] = ((d4.z & (NPB - 1)) << 17) | s4.z;
        bb = d4.w >> BINSHIFT; p = atomicAdd(&soff[bb], 1);
        if (p < BINCAP) binned[bb * BINCAP + p] = ((d4.w & (NPB - 1)) << 17) | s4.w;
    }
    if (b == NBLK - 1 && t == 0) {
        for (int e = (E & ~3); e < E; ++e) {
            int d = ei[E + e], bb = d >> BINSHIFT;
            int p = atomicAdd(&soff[bb], 1);
            if (p < BINCAP) binned[bb * BINCAP + p] = ((d & (NPB - 1)) << 17) | ei[e];
        }
    }
}

// ---------------- per-bin sort (two global passes, 1024 thr) -> CSR + deg/rowstart/dinv + xs0b ----

__global__ __launch_bounds__(1024) void bin_sort_k(
    const int* __restrict__ totals, const int* __restrict__ binned, const float* __restrict__ x,
    int* __restrict__ csr, int* __restrict__ deg, int* __restrict__ rowstart,
    float* __restrict__ dinv_g, ushort* __restrict__ xs0b, int N) {
    __shared__ int scnt[NPB];
    __shared__ int sscan[NPB];
    __shared__ int sfill[NPB];
    int bin = blockIdx.x;
    int t   = threadIdx.x;
    int total = totals[bin];
    if (total > BINCAP) total = BINCAP;
    if (t < NPB) { scnt[t] = 0; sfill[t] = 0; }
    __syncthreads();
    const int* gsrc = binned + bin * BINCAP;
    for (int i = t; i < total; i += 1024) atomicAdd(&scnt[gsrc[i] >> 17], 1);
    __syncthreads();
    if (t < NPB) sscan[t] = scnt[t];
    __syncthreads();
    for (int off = 1; off < NPB; off <<= 1) {       // inclusive Hillis-Steele over 512
        int a = (t < NPB && t >= off) ? sscan[t - off] : 0;
        __syncthreads();
        if (t < NPB) sscan[t] += a;
        __syncthreads();
    }
    int obase = bin * BINCAP;
    for (int i = t; i < total; i += 1024) {
        int rec = gsrc[i], n = rec >> 17;
        int r = atomicAdd(&sfill[n], 1);
        csr[obase + (sscan[n] - scnt[n]) + r] = rec & 0x1FFFF;
    }
    if (t < NPB) {
        int node = (bin << BINSHIFT) + t;
        if (node < N) {
            int c = scnt[t];
            deg[node]      = c;
            rowstart[node] = obase + sscan[t] - c;
            dinv_g[node]   = rsqrtf((float)(c + 1));
        }
    }
    int base = bin << BINSHIFT;
    for (int i = t; i < NPB * 8; i += 1024) {
        int nloc = i >> 3, c2 = i & 7;
        int node = base + nloc;
        if (node < N) {
            float di = rsqrtf((float)(scnt[nloc] + 1));
            int c0 = c2 * 2, c1 = c0 + 1;
            float a = (c0 < 14) ? x[node * 14 + c0] * di : 0.f;
            float b = (c1 < 14) ? x[node * 14 + c1] * di : 0.f;
            reinterpret_cast<uint*>(xs0b)[node * 8 + c2] = pack_bf2(a, b);
        }
    }
}

// ---------------- fused layer-1 agg + gemm ----------------
// xs0b bf16 [N,16] (dinv-scaled); 4 lanes/node, 4 ch/lane. After the gather the
// 4-lane group shfl-rebuilds the full 16-vec per lane; each lane computes its 16
// of the 64 outputs (224 FMA) and writes fp8(dinv*relu(row@W1+b1)) -> h1f8.

__global__ __launch_bounds__(256) void agg12_k(
    const ushort* __restrict__ xs, const int* __restrict__ deg, const int* __restrict__ rowstart,
    const int* __restrict__ csr, const float* __restrict__ dinv,
    const float* __restrict__ W1, const float* __restrict__ b1,
    uchar* __restrict__ h1f8, int N) {
    const int G = 4;
    __shared__ float sW1[14 * 64];
    __shared__ float sB1[64];
    int t = threadIdx.x;
    for (int i = t; i < 14 * 64; i += 256) sW1[i] = W1[i];
    if (t < 64) sB1[t] = b1[t];
    __syncthreads();
    int tid  = blockIdx.x * 256 + t;
    int lane = t & (WAVE - 1);
    int wave = tid >> 6;
    int node = wave * (WAVE / G) + lane / G;
    int cg   = lane % G;
    if (node >= N) return;
    int s = rowstart[node];
    int e = s + deg[node];
    float4 acc = {0.f, 0.f, 0.f, 0.f};
    for (int j = s; j < e; j += G) {
        int es = (j + cg < e) ? csr[j + cg] : -1;
#pragma unroll
        for (int k = 0; k < G; ++k) {
            int sk = __shfl(es, k, G);
            uint2 u = *reinterpret_cast<const uint2*>(xs + (long)sk * 16 + (cg << 2));
            acc.x += bflo(u.x); acc.y += bfhi(u.x);
            acc.z += bflo(u.y); acc.w += bfhi(u.y);
        }
    }
    {   // self-loop
        uint2 u = *reinterpret_cast<const uint2*>(xs + (long)node * 16 + (cg << 2));
        acc.x += bflo(u.x); acc.y += bfhi(u.x);
        acc.z += bflo(u.y); acc.w += bfhi(u.y);
    }
    float di = dinv[node];
    float r0 = acc.x * di, r1 = acc.y * di, r2 = acc.z * di, r3 = acc.w * di;
    float rr[16];
#pragma unroll
    for (int k = 0; k < 4; ++k) {
        rr[4 * k + 0] = __shfl(r0, k, G);
        rr[4 * k + 1] = __shfl(r1, k, G);
        rr[4 * k + 2] = __shfl(r2, k, G);
        rr[4 * k + 3] = __shfl(r3, k, G);
    }
    int ob = cg << 4;
    float a[16];
#pragma unroll
    for (int o = 0; o < 16; ++o) a[o] = sB1[ob + o];
#pragma unroll
    for (int c = 0; c < 14; ++c) {
        float rc = rr[c];
#pragma unroll
        for (int o = 0; o < 16; ++o) a[o] += rc * sW1[c * 64 + ob + o];
    }
    uint* orow = reinterpret_cast<uint*>(h1f8 + (long)node * 64 + ob);
#pragma unroll
    for (int o = 0; o < 16; o += 4) {
        float x0 = fmaxf(a[o + 0], 0.f) * di;
        float x1 = fmaxf(a[o + 1], 0.f) * di;
        float x2 = fmaxf(a[o + 2], 0.f) * di;
        float x3 = fmaxf(a[o + 3], 0.f) * di;
        orow[o >> 2] = fp8x4_enc(x0, x1, x2, x3);
    }
}

// ---------------- Aggregation over sorted CSR (layer 2: fp8 in, fp8 out) ----------------
// Widened sliver: 8 lanes/node, 8 fp8 ch/lane via uint2 (8 req/edge vs 16).

__global__ __launch_bounds__(256) void agg2_k(
    const uchar* __restrict__ xs, uchar* __restrict__ out,
    const int* __restrict__ deg, const int* __restrict__ rowstart, const int* __restrict__ csr,
    const float* __restrict__ dinv, int N) {
    const int G = 8;
    int tid  = blockIdx.x * blockDim.x + threadIdx.x;
    int lane = threadIdx.x & (WAVE - 1);
    int wave = tid >> 6;
    int node = wave * (WAVE / G) + lane / G;
    int cg   = lane % G;
    if (node >= N) return;
    int s = rowstart[node];
    int e = s + deg[node];
    float acc[8];
#pragma unroll
    for (int o = 0; o < 8; ++o) acc[o] = 0.f;
    for (int j = s; j < e; j += G) {
        int es = (j + cg < e) ? csr[j + cg] : -1;
#pragma unroll
        for (int k = 0; k < G; ++k) {
            int sk = __shfl(es, k, G);
            uint2 u = *reinterpret_cast<const uint2*>(xs + (long)sk * 64 + (cg << 3));
            float a0, a1, a2, a3;
            fp8x4_dec(u.x, a0, a1, a2, a3);
            acc[0] += a0; acc[1] += a1; acc[2] += a2; acc[3] += a3;
            fp8x4_dec(u.y, a0, a1, a2, a3);
            acc[4] += a0; acc[5] += a1; acc[6] += a2; acc[7] += a3;
        }
    }
    {   // self-loop
        uint2 u = *reinterpret_cast<const uint2*>(xs + (long)node * 64 + (cg << 3));
        float a0, a1, a2, a3;
        fp8x4_dec(u.x, a0, a1, a2, a3);
        acc[0] += a0; acc[1] += a1; acc[2] += a2; acc[3] += a3;
        fp8x4_dec(u.y, a0, a1, a2, a3);
        acc[4] += a0; acc[5] += a1; acc[6] += a2; acc[7] += a3;
    }
    float di = dinv[node];
    uint2 ov;
    ov.x = fp8x4_enc(acc[0] * di, acc[1] * di, acc[2] * di, acc[3] * di);
    ov.y = fp8x4_enc(acc[4] * di, acc[5] * di, acc[6] * di, acc[7] * di);
    *reinterpret_cast<uint2*>(out + (long)node * 64 + (cg << 3)) = ov;
}

// ---------------- MFMA fused layer-2 + layer-3 gemms (fp8 A-input) ----------------

#define GW 72

__global__ __launch_bounds__(256) void gemm23_k(
    const uchar* __restrict__ inb, const float* __restrict__ W2, const float* __restrict__ b2,
    const float* __restrict__ W3, const float* __restrict__ dinv,
    uchar* __restrict__ outp, int N) {
    __shared__ ushort sW2t[64 * GW];     // [n][k]
    __shared__ ushort sW3t[32 * GW];
    __shared__ float  sB2[64];
    __shared__ ushort sH[4][16 * GW];    // per-wave h tile [m][c]
    __shared__ uchar  sO[4][16 * 32];    // per-wave fp8 out tile
    int t = threadIdx.x;
    for (int i = t; i < 64 * 64; i += 256) {
        int k = i >> 6, n = i & 63;
        sW2t[n * GW + k] = bf16r(W2[k * 64 + n]);
    }
    for (int i = t; i < 64 * 32; i += 256) {
        int k = i >> 5, n = i & 31;
        sW3t[n * GW + k] = bf16r(W3[k * 32 + n]);
    }
    if (t < 64) sB2[t] = b2[t];
    __syncthreads();

    int w    = t >> 6;
    int lane = t & 63;
    int m16  = lane & 15;
    int q    = lane >> 4;
    int base = blockIdx.x * 64 + w * 16;

    const uint2* rp = reinterpret_cast<const uint2*>(inb + (long)(base + m16) * 64);
    uint2 ua = rp[q];        // channels q*8 .. q*8+8
    uint2 ub = rp[q + 4];    // channels 32+q*8 ..
    bf16x8 a0 = fp8x8_bf16(ua.x, ua.y);
    bf16x8 a1 = fp8x8_bf16(ub.x, ub.y);

    f32x4 acc1[4];
#pragma unroll
    for (int nt = 0; nt < 4; ++nt) {
        f32x4 c = {0.f, 0.f, 0.f, 0.f};
        bf16x8 b0 = *reinterpret_cast<const bf16x8*>(&sW2t[(nt * 16 + m16) * GW + q * 8]);
        bf16x8 b1 = *reinterpret_cast<const bf16x8*>(&sW2t[(nt * 16 + m16) * GW + 32 + q * 8]);
        c = __builtin_amdgcn_mfma_f32_16x16x32_bf16(a0, b0, c, 0, 0, 0);
        c = __builtin_amdgcn_mfma_f32_16x16x32_bf16(a1, b1, c, 0, 0, 0);
        acc1[nt] = c;
    }
    ushort* hT = sH[w];
#pragma unroll
    for (int nt = 0; nt < 4; ++nt) {
        float bb = sB2[nt * 16 + m16];
#pragma unroll
        for (int r = 0; r < 4; ++r) {
            float h = fmaxf(acc1[nt][r] + bb, 0.f);
            hT[(q * 4 + r) * GW + nt * 16 + m16] = bf16r(h);
        }
    }
    __syncthreads();
    bf16x8 a20 = *reinterpret_cast<const bf16x8*>(&hT[m16 * GW + q * 8]);
    bf16x8 a21 = *reinterpret_cast<const bf16x8*>(&hT[m16 * GW + 32 + q * 8]);
    f32x4 acc2[2];
#pragma unroll
    for (int nt = 0; nt < 2; ++nt) {
        f32x4 c = {0.f, 0.f, 0.f, 0.f};
        bf16x8 b0 = *reinterpret_cast<const bf16x8*>(&sW3t[(nt * 16 + m16) * GW + q * 8]);
        bf16x8 b1 = *reinterpret_cast<const bf16x8*>(&sW3t[(nt * 16 + m16) * GW + 32 + q * 8]);
        c = __builtin_amdgcn_mfma_f32_16x16x32_bf16(a20, b0, c, 0, 0, 0);
        c = __builtin_amdgcn_mfma_f32_16x16x32_bf16(a21, b1, c, 0, 0, 0);
        acc2[nt] = c;
    }
    uchar* oT = sO[w];
#pragma unroll
    for (int r = 0; r < 4; ++r) {
        int m = q * 4 + r;
        float di = dinv[min(base + m, N - 1)];
#pragma unroll
        for (int nt = 0; nt < 2; ++nt)
            oT[m * 32 + nt * 16 + m16] = (uchar)fp8_enc1(acc2[nt][r] * di);
    }
    __syncthreads();
    const uint* src = reinterpret_cast<const uint*>(oT);
    uint* dst = reinterpret_cast<uint*>(outp + (long)base * 32);
    dst[lane] = src[lane];
    dst[lane + 64] = src[lane + 64];
}

// ---------------- fused layer-3 agg + layer-4 gemm ----------------
// Widened sliver: 4 lanes/node, 8 fp8 ch/lane via uint2 (4 req/edge vs 8).
// Epilogue: 8 channels/lane through b3/relu/W4; reduce over 4 lanes (masks 2,1).

__global__ __launch_bounds__(256) void agg34_k(
    const uchar* __restrict__ xs, const int* __restrict__ deg, const int* __restrict__ rowstart,
    const int* __restrict__ csr, const float* __restrict__ dinv, const float* __restrict__ b3,
    const float* __restrict__ W4, ushort* __restrict__ usb, int N) {
    const int G = 4;
    __shared__ float sW4[64];   // W4[32][2]
    __shared__ float sB3[32];
    int t = threadIdx.x;
    if (t < 64) sW4[t] = W4[t];
    if (t < 32) sB3[t] = b3[t];
    __syncthreads();
    int tid  = blockIdx.x * 256 + t;
    int lane = t & (WAVE - 1);
    int wave = tid >> 6;
    int node = wave * (WAVE / G) + lane / G;
    int cg   = lane % G;
    if (node >= N) return;
    int s = rowstart[node];
    int e = s + deg[node];
    float acc[8];
#pragma unroll
    for (int o = 0; o < 8; ++o) acc[o] = 0.f;
    for (int j = s; j < e; j += G) {
        int es = (j + cg < e) ? csr[j + cg] : -1;
#pragma unroll
        for (int k = 0; k < G; ++k) {
            int sk = __shfl(es, k, G);
            uint2 u = *reinterpret_cast<const uint2*>(xs + (long)sk * 32 + (cg << 3));
            float a0, a1, a2, a3;
            fp8x4_dec(u.x, a0, a1, a2, a3);
            acc[0] += a0; acc[1] += a1; acc[2] += a2; acc[3] += a3;
            fp8x4_dec(u.y, a0, a1, a2, a3);
            acc[4] += a0; acc[5] += a1; acc[6] += a2; acc[7] += a3;
        }
    }
    {   // self-loop
        uint2 u = *reinterpret_cast<const uint2*>(xs + (long)node * 32 + (cg << 3));
        float a0, a1, a2, a3;
        fp8x4_dec(u.x, a0, a1, a2, a3);
        acc[0] += a0; acc[1] += a1; acc[2] += a2; acc[3] += a3;
        fp8x4_dec(u.y, a0, a1, a2, a3);
        acc[4] += a0; acc[5] += a1; acc[6] += a2; acc[7] += a3;
    }
    float di = dinv[node];
    int cb = cg << 3;            // 8 channels per lane
    float p0 = 0.f, p1 = 0.f;
#pragma unroll
    for (int o = 0; o < 8; ++o) {
        float h = fmaxf(acc[o] * di + sB3[cb + o], 0.f);
        p0 += h * sW4[(cb + o) * 2 + 0];
        p1 += h * sW4[(cb + o) * 2 + 1];
    }
#pragma unroll
    for (int o = 2; o >= 1; o >>= 1) {
        p0 += __shfl_xor(p0, o, WAVE);
        p1 += __shfl_xor(p1, o, WAVE);
    }
    if (cg == 0)
        reinterpret_cast<uint*>(usb)[node] = pack_bf2(p0 * di, p1 * di);
}

// ---------------- layer-4 aggregation, edge-parallel, atomic-free (bf16 [N,2]) ----------------

#define PG 16

__global__ __launch_bounds__(256) void agg4_k(
    const ushort* __restrict__ xs, const int* __restrict__ deg, const int* __restrict__ rowstart,
    const int* __restrict__ csr, const float* __restrict__ dinv, const float* __restrict__ bias,
    float* __restrict__ nodeout, int N) {
    int tid  = blockIdx.x * 256 + threadIdx.x;
    int lane = threadIdx.x & (WAVE - 1);
    int wave = tid >> 6;
    int node = wave * (WAVE / PG) + lane / PG;
    int l    = lane % PG;
    if (node >= N) return;
    int s = rowstart[node];
    int e = s + deg[node];
    float ax = 0.f, ay = 0.f;
    for (int j = s + l; j < e; j += PG) {
        int es = csr[j];
        uint u = *reinterpret_cast<const uint*>(xs + (long)es * 2);
        ax += bflo(u); ay += bfhi(u);
    }
#pragma unroll
    for (int o = PG / 2; o >= 1; o >>= 1) {
        ax += __shfl_xor(ax, o, WAVE);
        ay += __shfl_xor(ay, o, WAVE);
    }
    if (l == 0) {
        uint u = *reinterpret_cast<const uint*>(xs + (long)node * 2);
        ax += bflo(u); ay += bfhi(u);
        float di = dinv[node];
        float2 r;
        r.x = ax * di + bias[0];
        r.y = ay * di + bias[1];
        *reinterpret_cast<float2*>(nodeout + (long)node * 2) = r;
    }
}

// ---------------- per-graph max-pool + log_softmax ----------------

__global__ __launch_bounds__(256) void pool_g_k(
    const float* __restrict__ nodeout, const int* __restrict__ gstart,
    float* __restrict__ out, int Gn) {
    int wave = (blockIdx.x * 256 + threadIdx.x) >> 6;
    int lane = threadIdx.x & (WAVE - 1);
    if (wave >= Gn) return;
    int s = gstart[wave], e = gstart[wave + 1];
    float ax = -INFINITY, ay = -INFINITY;
    for (int i = s + lane; i < e; i += WAVE) {
        float2 v = *reinterpret_cast<const float2*>(nodeout + (long)i * 2);
        ax = fmaxf(ax, v.x); ay = fmaxf(ay, v.y);
    }
#pragma unroll
    for (int o = 32; o >= 1; o >>= 1) {
        ax = fmaxf(ax, __shfl_xor(ax, o, WAVE));
        ay = fmaxf(ay, __shfl_xor(ay, o, WAVE));
    }
    if (lane == 0) {
        if (!isfinite(ax)) ax = 0.f;
        if (!isfinite(ay)) ay = 0.f;
        float m = fmaxf(ax, ay);
        float lse = m + logf(expf(ax - m) + expf(ay - m));
        out[wave * 2 + 0] = ax - lse;
        out[wave * 2 + 1] = ay - lse;
    }
}

// ---------------- launch ----------------

static inline int agg_blocks(int N, int G) {
    long waves = ((long)N + (WAVE / G) - 1) / (WAVE / G);
    return (int)((waves * WAVE + 255) / 256);
}

extern "C" void kernel_launch(void* const* d_in, const int* in_sizes, int n_in,
                              void* d_out, int out_size, void* d_ws, size_t ws_size,
                              hipStream_t stream) {
    const float* x     = (const float*)d_in[0];
    const int*   ei    = (const int*)d_in[1];
    const int*   batch = (const int*)d_in[2];
    const float* W1 = (const float*)d_in[3];
    const float* b1 = (const float*)d_in[4];
    const float* W2 = (const float*)d_in[5];
    const float* b2 = (const float*)d_in[6];
    const float* W3 = (const float*)d_in[7];
    const float* b3 = (const float*)d_in[8];
    const float* W4 = (const float*)d_in[9];
    const float* b4 = (const float*)d_in[10];
    float* out = (float*)d_out;

    int N  = in_sizes[0] / 14;
    int E  = in_sizes[1] / 2;
    int Gn = out_size / 2;
    int nbins = (N + NPB - 1) >> BINSHIFT;   // 196

    char* ws = (char*)d_ws;
    size_t off = 0;
    auto alloc = [&](size_t bytes) -> char* {
        char* p = ws + off;
        off = (off + bytes + 255) & ~(size_t)255;
        return p;
    };
    int*    deg      = (int*)alloc((size_t)N * 4);
    int*    rowstart = (int*)alloc((size_t)N * 4);
    float*  dinv     = (float*)alloc((size_t)N * 4);
    int*    gstart   = (int*)alloc((size_t)(Gn + 1) * 4);
    int*    counts   = (int*)alloc((size_t)NBLK * nbins * 4);
    int*    prefix   = (int*)alloc((size_t)NBLK * nbins * 4);
    int*    totals   = (int*)alloc((size_t)nbins * 4);
    int*    csr      = (int*)alloc((size_t)nbins * BINCAP * 4);
    int*    binned   = (int*)alloc((size_t)nbins * BINCAP * 4);   // nodeout aliases after bin_sort
    ushort* padX     = (ushort*)alloc(256 + (size_t)N * 16 * 2);
    ushort* xs0b     = padX + 128;                 // bf16 [N,16]; usb [N,2] aliases later
    uint*   pad8     = (uint*)alloc(256 + (size_t)(N + 64) * 64);
    uchar*  h1f8     = (uchar*)(pad8 + 64);        // fp8 [N,64]; tsf8 [N+64,32] aliases later
    uchar*  Bf8      = (uchar*)alloc((size_t)(N + 64) * 64);      // fp8 [N+64,64] (MFMA tail pad)
    uchar*  tsf8     = h1f8;                       // dead after agg2
    ushort* usb      = xs0b;                       // dead after agg12
    float*  nodeout  = (float*)binned;             // dead after bin_sort
    (void)ws_size; (void)n_in;

    hist_k<<<NBLK, 1024, 0, stream>>>(ei, counts, E, nbins);
    scan_k<<<nbins, NBLK, 0, stream>>>(counts, prefix, totals, batch, gstart, padX, pad8, nbins, N, Gn);
    place_k<<<NBLK, 1024, 0, stream>>>(ei, prefix, binned, E, nbins);
    bin_sort_k<<<nbins, 1024, 0, stream>>>(totals, binned, x, csr, deg, rowstart, dinv, xs0b, N);

    // layer 1 fused: h1f8 = fp8(dinv*relu((dinv*(sum xs0b + self))@W1 + b1))
    agg12_k<<<agg_blocks(N, 4), 256, 0, stream>>>(xs0b, deg, rowstart, csr, dinv, W1, b1, h1f8, N);

    // layer 2: widened-sliver agg over h1f8 (fp8) -> Bf8 [N,64] fp8
    agg2_k<<<agg_blocks(N, 8), 256, 0, stream>>>(h1f8, Bf8, deg, rowstart, csr, dinv, N);

    // layers 2+3 gemms fused (MFMA, fp8 A-input): tsf8 = fp8(dinv*(relu(Bf8@W2+b2)@W3))
    gemm23_k<<<(N + 63) / 64, 256, 0, stream>>>(Bf8, W2, b2, W3, dinv, tsf8, N);

    // layer 3 agg + layer 4 gemm fused: usb = bf16(dinv*(relu(agg(tsf8)+b3)@W4))
    agg34_k<<<agg_blocks(N, 4), 256, 0, stream>>>(tsf8, deg, rowstart, csr, dinv, b3, W4, usb, N);

    // layer 4: atomic-free agg -> nodeout; per-graph pool+softmax
    agg4_k<<<agg_blocks(N, PG), 256, 0, stream>>>(usb, deg, rowstart, csr, dinv, b4, nodeout, N);
    pool_g_k<<<(Gn * WAVE + 255) / 256, 256, 0, stream>>>(nodeout, gstart, out, Gn);
}

// Round 8
// 270.318 us; speedup vs baseline: 1.0295x; 1.0295x over previous
//
#include <hip/hip_runtime.h>
#include <math.h>

#define WAVE 64
#define BINSHIFT 9                  // 512 nodes per bin
#define NPB 512                     // nodes per bin
#define NBLK 512                    // edge-tile blocks for hist/place (also scan block size)
#define MAXBINS 256                 // LDS histogram capacity (actual nbins = 196)
#define BINCAP 17408                // per-bin capacity; mean 16384, sd ~128 -> +8 sigma
// record packing: src < 2^17, dstLow < 512 -> rec = (dstLow<<17)|src fits 26 bits
//
// Round 5/7: per-edge global atomicAdd ~100+ MB fabric RMW -> build is atomic-free.
// Round 8: layer-2 agg L2-miss BW-bound -> gathered feature buffers bf16.
// Round 9/10: device atomicMax on sorted batch serializes -> atomic-free epilogue.
// Round 11/12/13: place_k scatter amp fixed via coarse bins (128 B segments).
// Round 14/15/16: fp8-e4m3 staging for layer-2/3 gathers.
// Round 17/18: MFMA gemm23 (16x16x32 bf16) replaced LDS-issue-bound scalar gemm.
// Round 19: bin_sort 1024 thr. Round 20: fuse agg1+gemm1 (best verified: 267.0).
// Round 21 FAILED (285.6): agg2+gemm23 fusion coupled gather behind barriers.
// Round 22/23 FAILED (315.9): channel-split kept req/edge high, doubled csr.
// Round 24/25 FAILED (286.5/283.6): row & pair-row gathers (VGPR pressure).
// Round 26 NEUTRAL (271.0): fp8 Bf8 staging — within noise, not better.
// Round 27 FAILED (278.3): widened slivers (G=8x8B / G=4x8B) — fewer
//   lanes/node costs more concurrency than halved request count saves.
// Round 28: full revert to the verified-best round-0 configuration (267.0).
//   Conclusion across R21-R27: the narrow-sliver gather at max lane
//   parallelism is latency-bound at an occupancy no alternative structure
//   beats; per-edge slivers coalesce to full 64B lines anyway. Pipeline is
//   at its practical plateau.

typedef int vint4 __attribute__((ext_vector_type(4)));
typedef unsigned int uint;
typedef unsigned char uchar;
typedef __attribute__((ext_vector_type(8))) short bf16x8;
typedef __attribute__((ext_vector_type(4))) float f32x4;

__device__ inline float bflo(uint u) { return __uint_as_float(u << 16); }
__device__ inline float bfhi(uint u) { return __uint_as_float(u & 0xffff0000u); }
__device__ inline uint pack_bf2(float a, float b) {   // a->low16, b->high16, RNE
    uint ua = __float_as_uint(a), ub = __float_as_uint(b);
    uint ra = (ua + 0x7fffu + ((ua >> 16) & 1u)) >> 16;
    uint rb = (ub + 0x7fffu + ((ub >> 16) & 1u)) & 0xffff0000u;
    return ra | rb;
}
__device__ inline ushort bf16r(float f) {             // RNE to bf16
    uint u = __float_as_uint(f);
    u += 0x7fffu + ((u >> 16) & 1u);
    return (ushort)(u >> 16);
}

// ---- fp8 e4m3fn (OCP) pack/unpack: HW cvt on gfx950, manual fallback ----

#if defined(__HIP_DEVICE_COMPILE__) && __has_builtin(__builtin_amdgcn_cvt_pk_f32_fp8) && __has_builtin(__builtin_amdgcn_cvt_pk_fp8_f32)
#define FP8_HW 1
#else
#define FP8_HW 0
#endif

__device__ inline uint fp8_enc1(float x) {            // manual e4m3fn encode, RNE
    float cx = fminf(fmaxf(x, -448.f), 448.f);
    uint s = (__float_as_uint(cx) >> 24) & 0x80u;
    float ax = fabsf(cx);
    uint r = __float_as_uint(ax);
    uint keep = r >> 20;
    uint rem = r & 0xFFFFFu;
    keep += (rem > 0x80000u || (rem == 0x80000u && (keep & 1u))) ? 1u : 0u;
    int em = (int)keep - (120 << 3);
    uint sub = (uint)__float2int_rn(ax * 512.f);      // subnormal grid 2^-9
    uint v = (ax >= 0.015625f) ? (uint)(em > 0x7E ? 0x7E : em) : sub;
    return s | v;
}
__device__ inline float fp8_dec1(uint b) {            // manual e4m3fn decode
    uint s = (b & 0x80u) << 24;
    uint em = b & 0x7Fu;
    float mag = (em >= 8u)
        ? __uint_as_float((((em >> 3) + 120u) << 23) | ((em & 7u) << 20))
        : (float)em * 0.001953125f;
    return __uint_as_float(s | __float_as_uint(mag));
}

__device__ inline uint fp8x4_enc(float a0, float a1, float a2, float a3) {
#if FP8_HW
    int v = __builtin_amdgcn_cvt_pk_fp8_f32(a0, a1, 0, 0);
    v     = __builtin_amdgcn_cvt_pk_fp8_f32(a2, a3, v, 1);
    return (uint)v;
#else
    return fp8_enc1(a0) | (fp8_enc1(a1) << 8) | (fp8_enc1(a2) << 16) | (fp8_enc1(a3) << 24);
#endif
}
__device__ inline void fp8x4_dec(uint u, float& a0, float& a1, float& a2, float& a3) {
#if FP8_HW
    auto lo = __builtin_amdgcn_cvt_pk_f32_fp8((int)u, 0);
    auto hi = __builtin_amdgcn_cvt_pk_f32_fp8((int)u, 1);
    a0 = lo[0]; a1 = lo[1]; a2 = hi[0]; a3 = hi[1];
#else
    a0 = fp8_dec1(u & 0xffu); a1 = fp8_dec1((u >> 8) & 0xffu);
    a2 = fp8_dec1((u >> 16) & 0xffu); a3 = fp8_dec1(u >> 24);
#endif
}

// ---------------- pass 1: per-block LDS histogram by bin (1024 thr) ----------------

__global__ __launch_bounds__(1024) void hist_k(const int* __restrict__ ei, int* __restrict__ counts,
                                               int E, int nbins) {
    __shared__ int scnt[MAXBINS];
    int t = threadIdx.x, b = blockIdx.x;
    if (t < nbins) scnt[t] = 0;
    __syncthreads();
    int nq  = E >> 2;
    int qpb = (nq + NBLK - 1) / NBLK;
    int q0 = b * qpb, q1 = min(q0 + qpb, nq);
    for (int q = q0 + t; q < q1; q += 1024) {
        vint4 d4 = __builtin_nontemporal_load(reinterpret_cast<const vint4*>(ei + E + q * 4));
        atomicAdd(&scnt[d4.x >> BINSHIFT], 1);
        atomicAdd(&scnt[d4.y >> BINSHIFT], 1);
        atomicAdd(&scnt[d4.z >> BINSHIFT], 1);
        atomicAdd(&scnt[d4.w >> BINSHIFT], 1);
    }
    if (b == NBLK - 1 && t == 0)
        for (int e = (E & ~3); e < E; ++e) atomicAdd(&scnt[ei[E + e] >> BINSHIFT], 1);
    __syncthreads();
    if (t < nbins) counts[b * nbins + t] = scnt[t];
}

// ---------------- scan (+ graph starts + sentinel pads) ----------------

__global__ __launch_bounds__(NBLK) void scan_k(const int* __restrict__ counts, int* __restrict__ prefix,
                                               int* __restrict__ totals, const int* __restrict__ batch,
                                               int* __restrict__ gstart, ushort* __restrict__ padX,
                                               uint* __restrict__ pad8, int nbins, int N, int Gn) {
    __shared__ int sm[NBLK];
    int bin = blockIdx.x, t = threadIdx.x;
    int v = counts[t * nbins + bin];
    sm[t] = v;
    __syncthreads();
    for (int off = 1; off < NBLK; off <<= 1) {
        int x = (t >= off) ? sm[t - off] : 0;
        __syncthreads();
        sm[t] += x;
        __syncthreads();
    }
    prefix[t * nbins + bin] = sm[t] - v;
    if (t == NBLK - 1) totals[bin] = sm[t];
    int gtid = bin * NBLK + t;
    if (gtid < N) {
        int bi = batch[gtid];
        int bp = (gtid == 0) ? -1 : batch[gtid - 1];
        for (int g = bp + 1; g <= bi; ++g) gstart[g] = gtid;
        if (gtid == N - 1)
            for (int g = bi + 1; g <= Gn; ++g) gstart[g] = N;
    }
    if (gtid < 128) padX[gtid] = 0;
    if (gtid < 64)  pad8[gtid] = 0;
}

// ---------------- pass 2: deterministic placement (1024 thr) ----------------

__global__ __launch_bounds__(1024) void place_k(const int* __restrict__ ei, const int* __restrict__ prefix,
                                                int* __restrict__ binned, int E, int nbins) {
    __shared__ int soff[MAXBINS];
    int t = threadIdx.x, b = blockIdx.x;
    if (t < nbins) soff[t] = prefix[b * nbins + t];
    __syncthreads();
    int nq  = E >> 2;
    int qpb = (nq + NBLK - 1) / NBLK;
    int q0 = b * qpb, q1 = min(q0 + qpb, nq);
    for (int q = q0 + t; q < q1; q += 1024) {
        vint4 s4 = __builtin_nontemporal_load(reinterpret_cast<const vint4*>(ei + q * 4));
        vint4 d4 = __builtin_nontemporal_load(reinterpret_cast<const vint4*>(ei + E + q * 4));
        int bb, p;
        bb = d4.x >> BINSHIFT; p = atomicAdd(&soff[bb], 1);
        if (p < BINCAP) binned[bb * BINCAP + p] = ((d4.x & (NPB - 1)) << 17) | s4.x;
        bb = d4.y >> BINSHIFT; p = atomicAdd(&soff[bb], 1);
        if (p < BINCAP) binned[bb * BINCAP + p] = ((d4.y & (NPB - 1)) << 17) | s4.y;
        bb = d4.z >> BINSHIFT; p = atomicAdd(&soff[bb], 1);
        if (p < BINCAP) binned[bb * BINCAP + p] = ((d4.z & (NPB - 1)) << 17) | s4.z;
        bb = d4.w >> BINSHIFT; p = atomicAdd(&soff[bb], 1);
        if (p < BINCAP) binned[bb * BINCAP + p] = ((d4.w & (NPB - 1)) << 17) | s4.w;
    }
    if (b == NBLK - 1 && t == 0) {
        for (int e = (E & ~3); e < E; ++e) {
            int d = ei[E + e], bb = d >> BINSHIFT;
            int p = atomicAdd(&soff[bb], 1);
            if (p < BINCAP) binned[bb * BINCAP + p] = ((d & (NPB - 1)) << 17) | ei[e];
        }
    }
}

// ---------------- per-bin sort (two global passes, 1024 thr) -> CSR + deg/rowstart/dinv + xs0b ----

__global__ __launch_bounds__(1024) void bin_sort_k(
    const int* __restrict__ totals, const int* __restrict__ binned, const float* __restrict__ x,
    int* __restrict__ csr, int* __restrict__ deg, int* __restrict__ rowstart,
    float* __restrict__ dinv_g, ushort* __restrict__ xs0b, int N) {
    __shared__ int scnt[NPB];
    __shared__ int sscan[NPB];
    __shared__ int sfill[NPB];
    int bin = blockIdx.x;
    int t   = threadIdx.x;
    int total = totals[bin];
    if (total > BINCAP) total = BINCAP;
    if (t < NPB) { scnt[t] = 0; sfill[t] = 0; }
    __syncthreads();
    const int* gsrc = binned + bin * BINCAP;
    for (int i = t; i < total; i += 1024) atomicAdd(&scnt[gsrc[i] >> 17], 1);
    __syncthreads();
    if (t < NPB) sscan[t] = scnt[t];
    __syncthreads();
    for (int off = 1; off < NPB; off <<= 1) {       // inclusive Hillis-Steele over 512
        int a = (t < NPB && t >= off) ? sscan[t - off] : 0;
        __syncthreads();
        if (t < NPB) sscan[t] += a;
        __syncthreads();
    }
    int obase = bin * BINCAP;
    for (int i = t; i < total; i += 1024) {
        int rec = gsrc[i], n = rec >> 17;
        int r = atomicAdd(&sfill[n], 1);
        csr[obase + (sscan[n] - scnt[n]) + r] = rec & 0x1FFFF;
    }
    if (t < NPB) {
        int node = (bin << BINSHIFT) + t;
        if (node < N) {
            int c = scnt[t];
            deg[node]      = c;
            rowstart[node] = obase + sscan[t] - c;
            dinv_g[node]   = rsqrtf((float)(c + 1));
        }
    }
    int base = bin << BINSHIFT;
    for (int i = t; i < NPB * 8; i += 1024) {
        int nloc = i >> 3, c2 = i & 7;
        int node = base + nloc;
        if (node < N) {
            float di = rsqrtf((float)(scnt[nloc] + 1));
            int c0 = c2 * 2, c1 = c0 + 1;
            float a = (c0 < 14) ? x[node * 14 + c0] * di : 0.f;
            float b = (c1 < 14) ? x[node * 14 + c1] * di : 0.f;
            reinterpret_cast<uint*>(xs0b)[node * 8 + c2] = pack_bf2(a, b);
        }
    }
}

// ---------------- fused layer-1 agg + gemm ----------------
// xs0b bf16 [N,16] (dinv-scaled); 4 lanes/node, 4 ch/lane. After the gather the
// 4-lane group shfl-rebuilds the full 16-vec per lane; each lane computes its 16
// of the 64 outputs (224 FMA) and writes fp8(dinv*relu(row@W1+b1)) -> h1f8.

__global__ __launch_bounds__(256) void agg12_k(
    const ushort* __restrict__ xs, const int* __restrict__ deg, const int* __restrict__ rowstart,
    const int* __restrict__ csr, const float* __restrict__ dinv,
    const float* __restrict__ W1, const float* __restrict__ b1,
    uchar* __restrict__ h1f8, int N) {
    const int G = 4;
    __shared__ float sW1[14 * 64];
    __shared__ float sB1[64];
    int t = threadIdx.x;
    for (int i = t; i < 14 * 64; i += 256) sW1[i] = W1[i];
    if (t < 64) sB1[t] = b1[t];
    __syncthreads();
    int tid  = blockIdx.x * 256 + t;
    int lane = t & (WAVE - 1);
    int wave = tid >> 6;
    int node = wave * (WAVE / G) + lane / G;
    int cg   = lane % G;
    if (node >= N) return;
    int s = rowstart[node];
    int e = s + deg[node];
    float4 acc = {0.f, 0.f, 0.f, 0.f};
    for (int j = s; j < e; j += G) {
        int es = (j + cg < e) ? csr[j + cg] : -1;
#pragma unroll
        for (int k = 0; k < G; ++k) {
            int sk = __shfl(es, k, G);
            uint2 u = *reinterpret_cast<const uint2*>(xs + (long)sk * 16 + (cg << 2));
            acc.x += bflo(u.x); acc.y += bfhi(u.x);
            acc.z += bflo(u.y); acc.w += bfhi(u.y);
        }
    }
    {   // self-loop
        uint2 u = *reinterpret_cast<const uint2*>(xs + (long)node * 16 + (cg << 2));
        acc.x += bflo(u.x); acc.y += bfhi(u.x);
        acc.z += bflo(u.y); acc.w += bfhi(u.y);
    }
    float di = dinv[node];
    float r0 = acc.x * di, r1 = acc.y * di, r2 = acc.z * di, r3 = acc.w * di;
    float rr[16];
#pragma unroll
    for (int k = 0; k < 4; ++k) {
        rr[4 * k + 0] = __shfl(r0, k, G);
        rr[4 * k + 1] = __shfl(r1, k, G);
        rr[4 * k + 2] = __shfl(r2, k, G);
        rr[4 * k + 3] = __shfl(r3, k, G);
    }
    int ob = cg << 4;
    float a[16];
#pragma unroll
    for (int o = 0; o < 16; ++o) a[o] = sB1[ob + o];
#pragma unroll
    for (int c = 0; c < 14; ++c) {
        float rc = rr[c];
#pragma unroll
        for (int o = 0; o < 16; ++o) a[o] += rc * sW1[c * 64 + ob + o];
    }
    uint* orow = reinterpret_cast<uint*>(h1f8 + (long)node * 64 + ob);
#pragma unroll
    for (int o = 0; o < 16; o += 4) {
        float x0 = fmaxf(a[o + 0], 0.f) * di;
        float x1 = fmaxf(a[o + 1], 0.f) * di;
        float x2 = fmaxf(a[o + 2], 0.f) * di;
        float x3 = fmaxf(a[o + 3], 0.f) * di;
        orow[o >> 2] = fp8x4_enc(x0, x1, x2, x3);
    }
}

// ---------------- Aggregation over sorted CSR (layer 2: fp8 in, bf16 out) ----------------

template <int CO, int G>
__global__ __launch_bounds__(256) void agg2_k(
    const uint* __restrict__ xs, ushort* __restrict__ out,
    const int* __restrict__ deg, const int* __restrict__ rowstart, const int* __restrict__ csr,
    const float* __restrict__ dinv, int N) {
    int tid  = blockIdx.x * blockDim.x + threadIdx.x;
    int lane = threadIdx.x & (WAVE - 1);
    int wave = tid >> 6;
    int node = wave * (WAVE / G) + lane / G;
    int cg   = lane % G;
    if (node >= N) return;
    int s = rowstart[node];
    int e = s + deg[node];
    float4 acc = {0.f, 0.f, 0.f, 0.f};
    for (int j = s; j < e; j += G) {
        int es = (j + cg < e) ? csr[j + cg] : -1;
#pragma unroll
        for (int k = 0; k < G; ++k) {
            int sk = __shfl(es, k, G);
            uint u = xs[(long)sk * G + cg];
            float a0, a1, a2, a3;
            fp8x4_dec(u, a0, a1, a2, a3);
            acc.x += a0; acc.y += a1; acc.z += a2; acc.w += a3;
        }
    }
    {   // self-loop
        uint u = xs[(long)node * G + cg];
        float a0, a1, a2, a3;
        fp8x4_dec(u, a0, a1, a2, a3);
        acc.x += a0; acc.y += a1; acc.z += a2; acc.w += a3;
    }
    float di = dinv[node];
    uint2 o;
    o.x = pack_bf2(acc.x * di, acc.y * di);
    o.y = pack_bf2(acc.z * di, acc.w * di);
    *reinterpret_cast<uint2*>(out + (long)node * CO + (cg << 2)) = o;
}

// ---------------- MFMA fused layer-2 + layer-3 gemms ----------------

#define GW 72

__global__ __launch_bounds__(256) void gemm23_k(
    const ushort* __restrict__ inb, const float* __restrict__ W2, const float* __restrict__ b2,
    const float* __restrict__ W3, const float* __restrict__ dinv,
    uchar* __restrict__ outp, int N) {
    __shared__ ushort sW2t[64 * GW];     // [n][k]
    __shared__ ushort sW3t[32 * GW];
    __shared__ float  sB2[64];
    __shared__ ushort sH[4][16 * GW];    // per-wave h tile [m][c]
    __shared__ uchar  sO[4][16 * 32];    // per-wave fp8 out tile
    int t = threadIdx.x;
    for (int i = t; i < 64 * 64; i += 256) {
        int k = i >> 6, n = i & 63;
        sW2t[n * GW + k] = bf16r(W2[k * 64 + n]);
    }
    for (int i = t; i < 64 * 32; i += 256) {
        int k = i >> 5, n = i & 31;
        sW3t[n * GW + k] = bf16r(W3[k * 32 + n]);
    }
    if (t < 64) sB2[t] = b2[t];
    __syncthreads();

    int w    = t >> 6;
    int lane = t & 63;
    int m16  = lane & 15;
    int q    = lane >> 4;
    int base = blockIdx.x * 64 + w * 16;

    bf16x8 a0 = *reinterpret_cast<const bf16x8*>(inb + (long)(base + m16) * 64 + q * 8);
    bf16x8 a1 = *reinterpret_cast<const bf16x8*>(inb + (long)(base + m16) * 64 + 32 + q * 8);

    f32x4 acc1[4];
#pragma unroll
    for (int nt = 0; nt < 4; ++nt) {
        f32x4 c = {0.f, 0.f, 0.f, 0.f};
        bf16x8 b0 = *reinterpret_cast<const bf16x8*>(&sW2t[(nt * 16 + m16) * GW + q * 8]);
        bf16x8 b1 = *reinterpret_cast<const bf16x8*>(&sW2t[(nt * 16 + m16) * GW + 32 + q * 8]);
        c = __builtin_amdgcn_mfma_f32_16x16x32_bf16(a0, b0, c, 0, 0, 0);
        c = __builtin_amdgcn_mfma_f32_16x16x32_bf16(a1, b1, c, 0, 0, 0);
        acc1[nt] = c;
    }
    ushort* hT = sH[w];
#pragma unroll
    for (int nt = 0; nt < 4; ++nt) {
        float bb = sB2[nt * 16 + m16];
#pragma unroll
        for (int r = 0; r < 4; ++r) {
            float h = fmaxf(acc1[nt][r] + bb, 0.f);
            hT[(q * 4 + r) * GW + nt * 16 + m16] = bf16r(h);
        }
    }
    __syncthreads();
    bf16x8 a20 = *reinterpret_cast<const bf16x8*>(&hT[m16 * GW + q * 8]);
    bf16x8 a21 = *reinterpret_cast<const bf16x8*>(&hT[m16 * GW + 32 + q * 8]);
    f32x4 acc2[2];
#pragma unroll
    for (int nt = 0; nt < 2; ++nt) {
        f32x4 c = {0.f, 0.f, 0.f, 0.f};
        bf16x8 b0 = *reinterpret_cast<const bf16x8*>(&sW3t[(nt * 16 + m16) * GW + q * 8]);
        bf16x8 b1 = *reinterpret_cast<const bf16x8*>(&sW3t[(nt * 16 + m16) * GW + 32 + q * 8]);
        c = __builtin_amdgcn_mfma_f32_16x16x32_bf16(a20, b0, c, 0, 0, 0);
        c = __builtin_amdgcn_mfma_f32_16x16x32_bf16(a21, b1, c, 0, 0, 0);
        acc2[nt] = c;
    }
    uchar* oT = sO[w];
#pragma unroll
    for (int r = 0; r < 4; ++r) {
        int m = q * 4 + r;
        float di = dinv[min(base + m, N - 1)];
#pragma unroll
        for (int nt = 0; nt < 2; ++nt)
            oT[m * 32 + nt * 16 + m16] = (uchar)fp8_enc1(acc2[nt][r] * di);
    }
    __syncthreads();
    const uint* src = reinterpret_cast<const uint*>(oT);
    uint* dst = reinterpret_cast<uint*>(outp + (long)base * 32);
    dst[lane] = src[lane];
    dst[lane + 64] = src[lane + 64];
}

// ---------------- fused layer-3 agg + layer-4 gemm ----------------

__global__ __launch_bounds__(256) void agg34_k(
    const uint* __restrict__ xs, const int* __restrict__ deg, const int* __restrict__ rowstart,
    const int* __restrict__ csr, const float* __restrict__ dinv, const float* __restrict__ b3,
    const float* __restrict__ W4, ushort* __restrict__ usb, int N) {
    const int G = 8;
    __shared__ float sW4[64];   // W4[32][2]
    __shared__ float sB3[32];
    int t = threadIdx.x;
    if (t < 64) sW4[t] = W4[t];
    if (t < 32) sB3[t] = b3[t];
    __syncthreads();
    int tid  = blockIdx.x * 256 + t;
    int lane = t & (WAVE - 1);
    int wave = tid >> 6;
    int node = wave * (WAVE / G) + lane / G;
    int cg   = lane % G;
    if (node >= N) return;
    int s = rowstart[node];
    int e = s + deg[node];
    float4 acc = {0.f, 0.f, 0.f, 0.f};
    for (int j = s; j < e; j += G) {
        int es = (j + cg < e) ? csr[j + cg] : -1;
#pragma unroll
        for (int k = 0; k < G; ++k) {
            int sk = __shfl(es, k, G);
            uint u = xs[(long)sk * G + cg];
            float a0, a1, a2, a3;
            fp8x4_dec(u, a0, a1, a2, a3);
            acc.x += a0; acc.y += a1; acc.z += a2; acc.w += a3;
        }
    }
    {   // self-loop
        uint u = xs[(long)node * G + cg];
        float a0, a1, a2, a3;
        fp8x4_dec(u, a0, a1, a2, a3);
        acc.x += a0; acc.y += a1; acc.z += a2; acc.w += a3;
    }
    float di = dinv[node];
    int cb = cg << 2;
    float h0 = fmaxf(acc.x * di + sB3[cb + 0], 0.f);
    float h1 = fmaxf(acc.y * di + sB3[cb + 1], 0.f);
    float h2 = fmaxf(acc.z * di + sB3[cb + 2], 0.f);
    float h3 = fmaxf(acc.w * di + sB3[cb + 3], 0.f);
    float p0 = h0 * sW4[(cb + 0) * 2 + 0] + h1 * sW4[(cb + 1) * 2 + 0]
             + h2 * sW4[(cb + 2) * 2 + 0] + h3 * sW4[(cb + 3) * 2 + 0];
    float p1 = h0 * sW4[(cb + 0) * 2 + 1] + h1 * sW4[(cb + 1) * 2 + 1]
             + h2 * sW4[(cb + 2) * 2 + 1] + h3 * sW4[(cb + 3) * 2 + 1];
#pragma unroll
    for (int o = 4; o >= 1; o >>= 1) {
        p0 += __shfl_xor(p0, o, WAVE);
        p1 += __shfl_xor(p1, o, WAVE);
    }
    if (cg == 0)
        reinterpret_cast<uint*>(usb)[node] = pack_bf2(p0 * di, p1 * di);
}

// ---------------- layer-4 aggregation, edge-parallel, atomic-free (bf16 [N,2]) ----------------

#define PG 16

__global__ __launch_bounds__(256) void agg4_k(
    const ushort* __restrict__ xs, const int* __restrict__ deg, const int* __restrict__ rowstart,
    const int* __restrict__ csr, const float* __restrict__ dinv, const float* __restrict__ bias,
    float* __restrict__ nodeout, int N) {
    int tid  = blockIdx.x * 256 + threadIdx.x;
    int lane = threadIdx.x & (WAVE - 1);
    int wave = tid >> 6;
    int node = wave * (WAVE / PG) + lane / PG;
    int l    = lane % PG;
    if (node >= N) return;
    int s = rowstart[node];
    int e = s + deg[node];
    float ax = 0.f, ay = 0.f;
    for (int j = s + l; j < e; j += PG) {
        int es = csr[j];
        uint u = *reinterpret_cast<const uint*>(xs + (long)es * 2);
        ax += bflo(u); ay += bfhi(u);
    }
#pragma unroll
    for (int o = PG / 2; o >= 1; o >>= 1) {
        ax += __shfl_xor(ax, o, WAVE);
        ay += __shfl_xor(ay, o, WAVE);
    }
    if (l == 0) {
        uint u = *reinterpret_cast<const uint*>(xs + (long)node * 2);
        ax += bflo(u); ay += bfhi(u);
        float di = dinv[node];
        float2 r;
        r.x = ax * di + bias[0];
        r.y = ay * di + bias[1];
        *reinterpret_cast<float2*>(nodeout + (long)node * 2) = r;
    }
}

// ---------------- per-graph max-pool + log_softmax ----------------

__global__ __launch_bounds__(256) void pool_g_k(
    const float* __restrict__ nodeout, const int* __restrict__ gstart,
    float* __restrict__ out, int Gn) {
    int wave = (blockIdx.x * 256 + threadIdx.x) >> 6;
    int lane = threadIdx.x & (WAVE - 1);
    if (wave >= Gn) return;
    int s = gstart[wave], e = gstart[wave + 1];
    float ax = -INFINITY, ay = -INFINITY;
    for (int i = s + lane; i < e; i += WAVE) {
        float2 v = *reinterpret_cast<const float2*>(nodeout + (long)i * 2);
        ax = fmaxf(ax, v.x); ay = fmaxf(ay, v.y);
    }
#pragma unroll
    for (int o = 32; o >= 1; o >>= 1) {
        ax = fmaxf(ax, __shfl_xor(ax, o, WAVE));
        ay = fmaxf(ay, __shfl_xor(ay, o, WAVE));
    }
    if (lane == 0) {
        if (!isfinite(ax)) ax = 0.f;
        if (!isfinite(ay)) ay = 0.f;
        float m = fmaxf(ax, ay);
        float lse = m + logf(expf(ax - m) + expf(ay - m));
        out[wave * 2 + 0] = ax - lse;
        out[wave * 2 + 1] = ay - lse;
    }
}

// ---------------- launch ----------------

static inline int agg_blocks(int N, int G) {
    long waves = ((long)N + (WAVE / G) - 1) / (WAVE / G);
    return (int)((waves * WAVE + 255) / 256);
}

extern "C" void kernel_launch(void* const* d_in, const int* in_sizes, int n_in,
                              void* d_out, int out_size, void* d_ws, size_t ws_size,
                              hipStream_t stream) {
    const float* x     = (const float*)d_in[0];
    const int*   ei    = (const int*)d_in[1];
    const int*   batch = (const int*)d_in[2];
    const float* W1 = (const float*)d_in[3];
    const float* b1 = (const float*)d_in[4];
    const float* W2 = (const float*)d_in[5];
    const float* b2 = (const float*)d_in[6];
    const float* W3 = (const float*)d_in[7];
    const float* b3 = (const float*)d_in[8];
    const float* W4 = (const float*)d_in[9];
    const float* b4 = (const float*)d_in[10];
    float* out = (float*)d_out;

    int N  = in_sizes[0] / 14;
    int E  = in_sizes[1] / 2;
    int Gn = out_size / 2;
    int nbins = (N + NPB - 1) >> BINSHIFT;   // 196

    char* ws = (char*)d_ws;
    size_t off = 0;
    auto alloc = [&](size_t bytes) -> char* {
        char* p = ws + off;
        off = (off + bytes + 255) & ~(size_t)255;
        return p;
    };
    int*    deg      = (int*)alloc((size_t)N * 4);
    int*    rowstart = (int*)alloc((size_t)N * 4);
    float*  dinv     = (float*)alloc((size_t)N * 4);
    int*    gstart   = (int*)alloc((size_t)(Gn + 1) * 4);
    int*    counts   = (int*)alloc((size_t)NBLK * nbins * 4);
    int*    prefix   = (int*)alloc((size_t)NBLK * nbins * 4);
    int*    totals   = (int*)alloc((size_t)nbins * 4);
    int*    csr      = (int*)alloc((size_t)nbins * BINCAP * 4);
    int*    binned   = (int*)alloc((size_t)nbins * BINCAP * 4);   // nodeout aliases after bin_sort
    ushort* padX     = (ushort*)alloc(256 + (size_t)N * 16 * 2);
    ushort* xs0b     = padX + 128;                 // bf16 [N,16]; usb [N,2] aliases later
    uint*   pad8     = (uint*)alloc(256 + (size_t)(N + 64) * 64);
    uchar*  h1f8     = (uchar*)(pad8 + 64);        // fp8 [N,64]; tsf8 [N+64,32] aliases later
    ushort* Bf1b     = (ushort*)alloc((size_t)(N + 64) * 64 * 2); // bf16 [N+64,64] (MFMA tail pad)
    uchar*  tsf8     = h1f8;                       // dead after agg2
    ushort* usb      = xs0b;                       // dead after agg12
    float*  nodeout  = (float*)binned;             // dead after bin_sort
    (void)ws_size; (void)n_in;

    hist_k<<<NBLK, 1024, 0, stream>>>(ei, counts, E, nbins);
    scan_k<<<nbins, NBLK, 0, stream>>>(counts, prefix, totals, batch, gstart, padX, pad8, nbins, N, Gn);
    place_k<<<NBLK, 1024, 0, stream>>>(ei, prefix, binned, E, nbins);
    bin_sort_k<<<nbins, 1024, 0, stream>>>(totals, binned, x, csr, deg, rowstart, dinv, xs0b, N);

    // layer 1 fused: h1f8 = fp8(dinv*relu((dinv*(sum xs0b + self))@W1 + b1))
    agg12_k<<<agg_blocks(N, 4), 256, 0, stream>>>(xs0b, deg, rowstart, csr, dinv, W1, b1, h1f8, N);

    // layer 2: agg over h1f8 (fp8, 6.4 MB) -> Bf1b [N,64] bf16
    agg2_k<64, 16><<<agg_blocks(N, 16), 256, 0, stream>>>((const uint*)h1f8, Bf1b, deg, rowstart, csr, dinv, N);

    // layers 2+3 gemms fused (MFMA): tsf8 = fp8(dinv*(relu(Bf1b@W2+b2)@W3))
    gemm23_k<<<(N + 63) / 64, 256, 0, stream>>>(Bf1b, W2, b2, W3, dinv, tsf8, N);

    // layer 3 agg + layer 4 gemm fused: usb = bf16(dinv*(relu(agg(tsf8)+b3)@W4))
    agg34_k<<<agg_blocks(N, 8), 256, 0, stream>>>((const uint*)tsf8, deg, rowstart, csr, dinv, b3, W4, usb, N);

    // layer 4: atomic-free agg -> nodeout; per-graph pool+softmax
    agg4_k<<<agg_blocks(N, PG), 256, 0, stream>>>(usb, deg, rowstart, csr, dinv, b4, nodeout, N);
    pool_g_k<<<(Gn * WAVE + 255) / 256, 256, 0, stream>>>(nodeout, gstart, out, Gn);
}